// Round 11
// baseline (841.909 us; speedup 1.0000x reference)
//
#include <hip/hip_runtime.h>
#include <cstdint>
#include <cstddef>

typedef unsigned short u16;
typedef __attribute__((ext_vector_type(4))) float f32x4;
typedef __attribute__((ext_vector_type(16))) float f32x16;
typedef __attribute__((ext_vector_type(8))) _Float16 f16x8;
typedef __attribute__((ext_vector_type(4))) u16   u16x4;
typedef __attribute__((ext_vector_type(8))) u16   u16x8;
typedef __attribute__((ext_vector_type(4))) int   i32x4;

#define DEV static __device__ __forceinline__
#define MFMA16(a,b,c) __builtin_amdgcn_mfma_f32_16x16x32_f16((a),(b),(c),0,0,0)
#define MFMA32(a,b,c) __builtin_amdgcn_mfma_f32_32x32x16_f16((a),(b),(c),0,0,0)

constexpr int Bc = 4, Cc = 256, Nc = 2048, Hc = 8, Dc = 256, OCc = 2048;

constexpr size_t OFF_XT = 0;
constexpr size_t OFF_YT = OFF_XT + (size_t)Bc*Nc*Cc*2;
constexpr size_t OFF_WQ = OFF_YT + (size_t)Bc*Nc*Cc*2;
constexpr size_t OFF_WK = OFF_WQ + (size_t)OCc*Cc*2;
constexpr size_t OFF_WV = OFF_WK + (size_t)OCc*Cc*2;
constexpr size_t OFF_BQ = OFF_WV + (size_t)OCc*Cc*2;
constexpr size_t OFF_BK = OFF_BQ + (size_t)OCc*4;
constexpr size_t OFF_BV = OFF_BK + (size_t)OCc*4;
constexpr size_t OFF_Q  = OFF_BV + (size_t)OCc*4;              // (B,H,N,D) f16
constexpr size_t OFF_K  = OFF_Q  + (size_t)Bc*Hc*Nc*Dc*2;      // (B,H,N,D) f16
constexpr size_t OFF_V  = OFF_K  + (size_t)Bc*Hc*Nc*Dc*2;      // (B,H,D,N) f16 (V^T)

DEV u16 f2h(float x){
  _Float16 h = (_Float16)x;
  return __builtin_bit_cast(u16, h);
}

DEV void load_lds16(const void* g, void* l){
  __builtin_amdgcn_global_load_lds((const __attribute__((address_space(1))) int*)g,
                                   (__attribute__((address_space(3))) int*)l, 16, 0, 0);
}

// ---------------- kernel 0a: transpose + cast x,y -> X^T f16 (B,N,C) ----------------
__global__ __launch_bounds__(256) void transpose_cast(const float* __restrict__ x,
                                                      const float* __restrict__ y,
                                                      u16* __restrict__ XT,
                                                      u16* __restrict__ YT){
  __shared__ u16 tile[64][65];
  int b = blockIdx.z >> 1;
  const float* src = (blockIdx.z & 1) ? y : x;
  u16* dst = (blockIdx.z & 1) ? YT : XT;
  int n0 = blockIdx.x * 64, c0 = blockIdx.y * 64;
  int t = threadIdx.x;
#pragma unroll
  for (int i = 0; i < 16; ++i){
    int slot = i*256 + t;
    int cl = slot >> 6, nl = slot & 63;
    tile[cl][nl] = f2h(src[((size_t)b*Cc + c0 + cl)*Nc + n0 + nl]);
  }
  __syncthreads();
#pragma unroll
  for (int i = 0; i < 8; ++i){
    int slot = i*256 + t;
    int nl = slot >> 5, cl = (slot & 31)*2;
    uint32_t v = (uint32_t)tile[cl][nl] | ((uint32_t)tile[cl+1][nl] << 16);
    *(uint32_t*)(dst + ((size_t)b*Nc + n0 + nl)*Cc + c0 + cl) = v;
  }
}

// ---------------- kernel 0b: fold g into W (f16), bias = g*b+beta ----------------
__global__ __launch_bounds__(256) void prep_w(const float* __restrict__ W,
                                              const float* __restrict__ bsrc,
                                              const float* __restrict__ g,
                                              const float* __restrict__ beta,
                                              u16* __restrict__ Wo,
                                              float* __restrict__ bb){
  int idx = (blockIdx.x*256 + threadIdx.x) * 8;
  int o = idx >> 8, c = idx & 255;
  float gg = g[o];
  f32x4 a0 = *(const f32x4*)(W + idx);
  f32x4 a1 = *(const f32x4*)(W + idx + 4);
  u16x8 r;
#pragma unroll
  for (int i = 0; i < 4; ++i){ r[i] = f2h(a0[i]*gg); r[i+4] = f2h(a1[i]*gg); }
  *(u16x8*)(Wo + idx) = r;
  if (c == 0) bb[o] = gg*bsrc[o] + beta[o];
}

// ---------------- kernel 1: projection GEMM (unchanged, verified) ----------------
template<int SW>
__global__ __launch_bounds__(256, 2) void proj_gemm(const u16* __restrict__ Xt,
                                                    const u16* __restrict__ Wp,
                                                    const float* __restrict__ bb,
                                                    u16* __restrict__ outp){
  __shared__ __align__(16) char lds[32768];
  int t = threadIdx.x, w = t >> 6, l = t & 63, q = l & 15, g = l >> 4;
  int b = blockIdx.z;
  int n0 = blockIdx.x * 128, o0 = blockIdx.y * 128;
  int fs = ((q >> 1) & 3) << 4;
  int partg = ((l & 3) ^ ((l >> 3) & 3));
  f32x4 acc[4][4] = {};

  for (int it = 0; it < 4; ++it){
    __syncthreads();
#pragma unroll
    for (int j = 0; j < 8; ++j){
      int s = j*4 + w;
      int chunk = s >> 3;
      int off = (s & 7) * 1024;
      int row = (s & 7)*16 + (l >> 2);
      const char* gsrc;
      if (chunk < 2)
        gsrc = (const char*)(Wp + (size_t)(o0 + row)*Cc) + it*128 + chunk*64 + partg*16;
      else
        gsrc = (const char*)(Xt + ((size_t)b*Nc + n0 + row)*Cc) + it*128 + (chunk & 1)*64 + partg*16;
      load_lds16(gsrc, lds + chunk*8192 + off);
    }
    asm volatile("s_waitcnt vmcnt(0)" ::: "memory");
    __syncthreads();
#pragma unroll
    for (int kc = 0; kc < 2; ++kc){
      f16x8 fw[4], fx[4];
#pragma unroll
      for (int i = 0; i < 4; ++i){
        int wrow = (SW ? (w & 1) : (w >> 1))*64 + i*16 + q;
        int xrow = (SW ? (w >> 1) : (w & 1))*64 + i*16 + q;
        fw[i] = *(const f16x8*)(lds + kc*8192 + wrow*64 + ((g*16) ^ fs));
        fx[i] = *(const f16x8*)(lds + 16384 + kc*8192 + xrow*64 + ((g*16) ^ fs));
      }
#pragma unroll
      for (int i = 0; i < 4; ++i)
#pragma unroll
        for (int jj = 0; jj < 4; ++jj){
          if constexpr (!SW) acc[i][jj] = MFMA16(fw[i], fx[jj], acc[i][jj]);
          else               acc[i][jj] = MFMA16(fx[i], fw[jj], acc[i][jj]);
        }
    }
  }

  if constexpr (!SW) {
    f32x4 bias[4];
#pragma unroll
    for (int i = 0; i < 4; ++i) bias[i] = *(const f32x4*)(bb + o0 + (w>>1)*64 + i*16 + 4*g);
#pragma unroll
    for (int i = 0; i < 4; ++i)
#pragma unroll
      for (int jj = 0; jj < 4; ++jj){
        u16x4 pk;
#pragma unroll
        for (int r = 0; r < 4; ++r){
          float z = acc[i][jj][r] + bias[i][r];
          pk[r] = f2h(fmaxf(z, 0.f));
        }
        int o = o0 + (w>>1)*64 + i*16 + 4*g;
        int n = n0 + (w&1)*64 + jj*16 + q;
        int hh = o >> 8, d = o & 255;
        *(u16x4*)(outp + ((size_t)((b*Hc + hh)*Nc + n))*Dc + d) = pk;
      }
  } else {
    float biasv[4];
#pragma unroll
    for (int i = 0; i < 4; ++i) biasv[i] = bb[o0 + (w&1)*64 + i*16 + q];
#pragma unroll
    for (int i = 0; i < 4; ++i)
#pragma unroll
      for (int jj = 0; jj < 4; ++jj){
        u16x4 pk;
#pragma unroll
        for (int r = 0; r < 4; ++r){
          float z = acc[i][jj][r] + biasv[jj];
          pk[r] = f2h(fmaxf(z, 0.f));
        }
        int o = o0 + (w&1)*64 + jj*16 + q;
        int n = n0 + (w>>1)*64 + i*16 + 4*g;
        int hh = o >> 8, d = o & 255;
        *(u16x4*)(outp + ((size_t)((b*Hc + hh)*Dc + d))*Nc + n) = pk;
      }
  }
}

// ---------------- kernel 2: flash attention, R10 core in 8-wave geometry ----------------
// 512 thr (wq 0..3 x wd 0..1), QBLK=128, launch_bounds(512,1) -> VGPR cap 256 (no spill).
// Wave: 32 q, full m=64 (QK dup x2 across wd), half d (acc 64). Wave-local softmax,
// in-register P pack (R10-verified). K: LDS dbuf [64m][512B], 5-bit scramble.
// V: direct global->reg, 2 batches (vA pre-QK, vB after vmcnt(8)). 1 barrier/iter.
__global__ __launch_bounds__(512, 1) void attn_kernel(const u16* __restrict__ Qp,
                                                      const u16* __restrict__ Kp,
                                                      const u16* __restrict__ Vp,
                                                      float* __restrict__ outp){
  __shared__ __align__(16) char lds[65536];   // K double buffer
  const int t = threadIdx.x, w = t >> 6, l = t & 63, lq = l & 31, hi = l >> 5;
  const int wq = w & 3, wd = w >> 2;
  const int h = blockIdx.y, b = blockIdx.z;
  const int q0 = blockIdx.x * 128;
  size_t head = (size_t)(b*Hc + h) * Nc * Dc;
  const u16* Qh = Qp + head;
  const u16* Kh = Kp + head;
  const u16* Vh = Vp + head;

  // Q B-frags: lane(lq,hi) holds Q[q0+wq*32+lq][kc*16 + hi*8 + e]
  f16x8 qf[16];
  {
    const u16* qrow = Qh + (size_t)(q0 + wq*32 + lq) * Dc;
#pragma unroll
    for (int kc = 0; kc < 16; ++kc) qf[kc] = *(const f16x8*)(qrow + kc*16 + hi*8);
  }

  f32x16 acc[4] = {};                 // O[32q][d-half: dt 0..3, col d = wd*128+dt*32+lq]
  float m_run = -1e30f, l_run = 0.f;
  const int lsw = lq ^ ((lq >> 3) & 3);   // read-side bank scramble

  // K staging: 8 waves x 4 insts x 2 rows = 64 rows; source chunk pre-scrambled
#define STAGE_K(m0_, buf_)                                                         \
  {                                                                                \
    char* Kd = lds + (buf_)*32768;                                                 \
    _Pragma("unroll")                                                              \
    for (int j = 0; j < 4; ++j){                                                   \
      int row = w*8 + j*2 + hi;                                                    \
      int r5 = row & 31;                                                           \
      int gs = (l & 31) ^ r5 ^ ((r5 >> 3) & 3);                                    \
      load_lds16(Kh + (size_t)((m0_) + row)*Dc + gs*8, Kd + w*4096 + j*1024);      \
    }                                                                              \
  }

  STAGE_K(0, 0);
  asm volatile("s_waitcnt vmcnt(0)" ::: "memory");
  __syncthreads();

  for (int it = 0; it < 32; ++it){
    const int cur = it & 1;
    const int m0 = it * 64;
    const int mn = ((it < 31) ? (it + 1) : 31) * 64;
    char* Kc = lds + cur*32768;

    // V batch A (m 0..31) issued first: 8 oldest vmem ops, hidden under QK
    f16x8 vA[8];
#pragma unroll
    for (int ks = 0; ks < 2; ++ks)
#pragma unroll
      for (int dt = 0; dt < 4; ++dt)
        vA[ks*4 + dt] = *(const f16x8*)(Vh + (size_t)(wd*128 + dt*32 + lq)*Nc + m0 + ks*16 + hi*8);

    // stage K(t+1) into other buffer
    STAGE_K(mn, cur ^ 1);

    // QK^T both strips: S^T[m 0..63][32 q]
    f32x16 s0 = {}, s1 = {};
    __builtin_amdgcn_s_setprio(1);
#pragma unroll
    for (int kc = 0; kc < 16; ++kc){
      int so = ((kc*2 + hi) ^ lsw) << 4;
      f16x8 kf0 = *(const f16x8*)(Kc + lq*512 + so);
      f16x8 kf1 = *(const f16x8*)(Kc + (32 + lq)*512 + so);
      s0 = MFMA32(kf0, qf[kc], s0);
      s1 = MFMA32(kf1, qf[kc], s1);
    }
    __builtin_amdgcn_s_setprio(0);

    // wave-local softmax (lane owns q-col lq, dup across hi)
    float tmax = s0[0];
#pragma unroll
    for (int r = 1; r < 16; ++r) tmax = fmaxf(tmax, s0[r]);
#pragma unroll
    for (int r = 0; r < 16; ++r) tmax = fmaxf(tmax, s1[r]);
    tmax = fmaxf(tmax, __shfl_xor(tmax, 32));

    float meff = m_run, scale = 1.f;
    if (!__all(tmax <= m_run + 8.f)){       // T13 defer-max
      meff = fmaxf(m_run, tmax);
      scale = __expf(m_run - meff);
      m_run = meff;
#pragma unroll
      for (int r = 0; r < 16; ++r){
        float scr = __shfl(scale, (r & 3) + 8*(r >> 2) + 4*hi);
#pragma unroll
        for (int dt = 0; dt < 4; ++dt) acc[dt][r] *= scr;
      }
    }

    float rsum = 0.f;
#pragma unroll
    for (int r = 0; r < 16; ++r){ s0[r] = __expf(s0[r] - meff); rsum += s0[r]; }
#pragma unroll
    for (int r = 0; r < 16; ++r){ s1[r] = __expf(s1[r] - meff); rsum += s1[r]; }
    rsum += __shfl_xor(rsum, 32);
    l_run = l_run * scale + rsum;

    // pack P in-register (verified): strip0 -> a0,a1 ; strip1 -> a2,a3
    f16x8 a0, a1, a2, a3;
    {
      int pk[8], sx[8];
#pragma unroll
      for (int j2 = 0; j2 < 8; ++j2)
        pk[j2] = __builtin_bit_cast(int, __builtin_amdgcn_cvt_pkrtz(s0[2*j2], s0[2*j2+1]));
#pragma unroll
      for (int j2 = 0; j2 < 8; ++j2) sx[j2] = __shfl_xor(pk[j2], 32);
      i32x4 c0, c1;
      c0[0] = hi ? sx[2] : pk[0];  c0[1] = hi ? sx[3] : pk[1];
      c0[2] = hi ? pk[2] : sx[0];  c0[3] = hi ? pk[3] : sx[1];
      c1[0] = hi ? sx[6] : pk[4];  c1[1] = hi ? sx[7] : pk[5];
      c1[2] = hi ? pk[6] : sx[4];  c1[3] = hi ? pk[7] : sx[5];
      a0 = __builtin_bit_cast(f16x8, c0);
      a1 = __builtin_bit_cast(f16x8, c1);
    }
    {
      int pk[8], sx[8];
#pragma unroll
      for (int j2 = 0; j2 < 8; ++j2)
        pk[j2] = __builtin_bit_cast(int, __builtin_amdgcn_cvt_pkrtz(s1[2*j2], s1[2*j2+1]));
#pragma unroll
      for (int j2 = 0; j2 < 8; ++j2) sx[j2] = __shfl_xor(pk[j2], 32);
      i32x4 c0, c1;
      c0[0] = hi ? sx[2] : pk[0];  c0[1] = hi ? sx[3] : pk[1];
      c0[2] = hi ? pk[2] : sx[0];  c0[3] = hi ? pk[3] : sx[1];
      c1[0] = hi ? sx[6] : pk[4];  c1[1] = hi ? sx[7] : pk[5];
      c1[2] = hi ? pk[6] : sx[4];  c1[3] = hi ? pk[7] : sx[5];
      a2 = __builtin_bit_cast(f16x8, c0);
      a3 = __builtin_bit_cast(f16x8, c1);
    }

    // vA ready (8 oldest of [vA 8][K 8])
    asm volatile("s_waitcnt vmcnt(8)" ::: "memory");

    // V batch B (m 32..63): hidden under PV1
    f16x8 vB[8];
#pragma unroll
    for (int ks = 0; ks < 2; ++ks)
#pragma unroll
      for (int dt = 0; dt < 4; ++dt)
        vB[ks*4 + dt] = *(const f16x8*)(Vh + (size_t)(wd*128 + dt*32 + lq)*Nc + m0 + 32 + ks*16 + hi*8);

    // PV half 1 (m 0..31)
    __builtin_amdgcn_s_setprio(1);
#pragma unroll
    for (int dt = 0; dt < 4; ++dt){
      acc[dt] = MFMA32(a0, vA[dt],     acc[dt]);
      acc[dt] = MFMA32(a1, vA[4 + dt], acc[dt]);
    }
    __builtin_amdgcn_s_setprio(0);

    // drain vB + K(t+1)
    asm volatile("s_waitcnt vmcnt(0)" ::: "memory");

    // PV half 2 (m 32..63)
    __builtin_amdgcn_s_setprio(1);
#pragma unroll
    for (int dt = 0; dt < 4; ++dt){
      acc[dt] = MFMA32(a2, vB[dt],     acc[dt]);
      acc[dt] = MFMA32(a3, vB[4 + dt], acc[dt]);
    }
    __builtin_amdgcn_s_setprio(0);

    __syncthreads();                      // buffer swap
  }
#undef STAGE_K

  float inv_own = 1.f / l_run;
#pragma unroll
  for (int r = 0; r < 16; ++r){
    int crow = (r & 3) + 8*(r >> 2) + 4*hi;
    float invr = __shfl(inv_own, crow);
    size_t obase = head + (size_t)(q0 + wq*32 + crow)*Dc + wd*128 + lq;
#pragma unroll
    for (int dt = 0; dt < 4; ++dt)
      outp[obase + dt*32] = acc[dt][r] * invr;
  }
}

// ---------------- launch ----------------
extern "C" void kernel_launch(void* const* d_in, const int* in_sizes, int n_in,
                              void* d_out, int out_size, void* d_ws, size_t ws_size,
                              hipStream_t stream){
  const float* x     = (const float*)d_in[0];
  const float* y     = (const float*)d_in[1];
  const float* Wq    = (const float*)d_in[2];
  const float* bq    = (const float*)d_in[3];
  const float* gq    = (const float*)d_in[4];
  const float* betaq = (const float*)d_in[5];
  const float* Wk    = (const float*)d_in[6];
  const float* bk    = (const float*)d_in[7];
  const float* gk    = (const float*)d_in[8];
  const float* betak = (const float*)d_in[9];
  const float* Wv    = (const float*)d_in[10];
  const float* bv    = (const float*)d_in[11];
  const float* gv    = (const float*)d_in[12];
  const float* betav = (const float*)d_in[13];
  char* ws = (char*)d_ws;
  float* outp = (float*)d_out;

  u16* XT = (u16*)(ws + OFF_XT);
  u16* YT = (u16*)(ws + OFF_YT);
  u16* WQb = (u16*)(ws + OFF_WQ);
  u16* WKb = (u16*)(ws + OFF_WK);
  u16* WVb = (u16*)(ws + OFF_WV);
  float* BQ = (float*)(ws + OFF_BQ);
  float* BK = (float*)(ws + OFF_BK);
  float* BV = (float*)(ws + OFF_BV);
  u16* Qw = (u16*)(ws + OFF_Q);
  u16* Kw = (u16*)(ws + OFF_K);
  u16* Vw = (u16*)(ws + OFF_V);

  transpose_cast<<<dim3(Nc/64, Cc/64, Bc*2), 256, 0, stream>>>(x, y, XT, YT);
  prep_w<<<dim3(OCc*Cc/2048), 256, 0, stream>>>(Wq, bq, gq, betaq, WQb, BQ);
  prep_w<<<dim3(OCc*Cc/2048), 256, 0, stream>>>(Wk, bk, gk, betak, WKb, BK);
  prep_w<<<dim3(OCc*Cc/2048), 256, 0, stream>>>(Wv, bv, gv, betav, WVb, BV);

  dim3 pg(Nc/128, OCc/128, Bc);
  proj_gemm<0><<<pg, 256, 0, stream>>>(XT, WQb, BQ, Qw);
  proj_gemm<0><<<pg, 256, 0, stream>>>(YT, WKb, BK, Kw);
  proj_gemm<1><<<pg, 256, 0, stream>>>(YT, WVb, BV, Vw);

  attn_kernel<<<dim3(Nc/128, Hc, Bc), 512, 0, stream>>>(Qw, Kw, Vw, outp);
}

// Round 12
// 405.552 us; speedup vs baseline: 2.0760x; 2.0760x over previous
//
#include <hip/hip_runtime.h>
#include <cstdint>
#include <cstddef>

typedef unsigned short u16;
typedef __attribute__((ext_vector_type(4))) float f32x4;
typedef __attribute__((ext_vector_type(16))) float f32x16;
typedef __attribute__((ext_vector_type(8))) _Float16 f16x8;
typedef __attribute__((ext_vector_type(4))) u16   u16x4;
typedef __attribute__((ext_vector_type(8))) u16   u16x8;
typedef __attribute__((ext_vector_type(4))) int   i32x4;

#define DEV static __device__ __forceinline__
#define MFMA16(a,b,c) __builtin_amdgcn_mfma_f32_16x16x32_f16((a),(b),(c),0,0,0)
#define MFMA32(a,b,c) __builtin_amdgcn_mfma_f32_32x32x16_f16((a),(b),(c),0,0,0)

constexpr int Bc = 4, Cc = 256, Nc = 2048, Hc = 8, Dc = 256, OCc = 2048;

constexpr size_t OFF_XT = 0;
constexpr size_t OFF_YT = OFF_XT + (size_t)Bc*Nc*Cc*2;
constexpr size_t OFF_WQ = OFF_YT + (size_t)Bc*Nc*Cc*2;
constexpr size_t OFF_WK = OFF_WQ + (size_t)OCc*Cc*2;
constexpr size_t OFF_WV = OFF_WK + (size_t)OCc*Cc*2;
constexpr size_t OFF_BQ = OFF_WV + (size_t)OCc*Cc*2;
constexpr size_t OFF_BK = OFF_BQ + (size_t)OCc*4;
constexpr size_t OFF_BV = OFF_BK + (size_t)OCc*4;
constexpr size_t OFF_Q  = OFF_BV + (size_t)OCc*4;              // (B,H,N,D) f16
constexpr size_t OFF_K  = OFF_Q  + (size_t)Bc*Hc*Nc*Dc*2;      // (B,H,N,D) f16
constexpr size_t OFF_V  = OFF_K  + (size_t)Bc*Hc*Nc*Dc*2;      // (B,H,D,N) f16 (V^T)

DEV u16 f2h(float x){
  _Float16 h = (_Float16)x;
  return __builtin_bit_cast(u16, h);
}

DEV void load_lds16(const void* g, void* l){
  __builtin_amdgcn_global_load_lds((const __attribute__((address_space(1))) int*)g,
                                   (__attribute__((address_space(3))) int*)l, 16, 0, 0);
}

// ---------------- kernel 0a: transpose + cast x,y -> X^T f16 (B,N,C) ----------------
__global__ __launch_bounds__(256) void transpose_cast(const float* __restrict__ x,
                                                      const float* __restrict__ y,
                                                      u16* __restrict__ XT,
                                                      u16* __restrict__ YT){
  __shared__ u16 tile[64][65];
  int b = blockIdx.z >> 1;
  const float* src = (blockIdx.z & 1) ? y : x;
  u16* dst = (blockIdx.z & 1) ? YT : XT;
  int n0 = blockIdx.x * 64, c0 = blockIdx.y * 64;
  int t = threadIdx.x;
#pragma unroll
  for (int i = 0; i < 16; ++i){
    int slot = i*256 + t;
    int cl = slot >> 6, nl = slot & 63;
    tile[cl][nl] = f2h(src[((size_t)b*Cc + c0 + cl)*Nc + n0 + nl]);
  }
  __syncthreads();
#pragma unroll
  for (int i = 0; i < 8; ++i){
    int slot = i*256 + t;
    int nl = slot >> 5, cl = (slot & 31)*2;
    uint32_t v = (uint32_t)tile[cl][nl] | ((uint32_t)tile[cl+1][nl] << 16);
    *(uint32_t*)(dst + ((size_t)b*Nc + n0 + nl)*Cc + c0 + cl) = v;
  }
}

// ---------------- kernel 0b: fold g into W (f16), bias = g*b+beta ----------------
__global__ __launch_bounds__(256) void prep_w(const float* __restrict__ W,
                                              const float* __restrict__ bsrc,
                                              const float* __restrict__ g,
                                              const float* __restrict__ beta,
                                              u16* __restrict__ Wo,
                                              float* __restrict__ bb){
  int idx = (blockIdx.x*256 + threadIdx.x) * 8;
  int o = idx >> 8, c = idx & 255;
  float gg = g[o];
  f32x4 a0 = *(const f32x4*)(W + idx);
  f32x4 a1 = *(const f32x4*)(W + idx + 4);
  u16x8 r;
#pragma unroll
  for (int i = 0; i < 4; ++i){ r[i] = f2h(a0[i]*gg); r[i+4] = f2h(a1[i]*gg); }
  *(u16x8*)(Wo + idx) = r;
  if (c == 0) bb[o] = gg*bsrc[o] + beta[o];
}

// ---------------- kernel 1: projection GEMM (unchanged, verified) ----------------
template<int SW>
__global__ __launch_bounds__(256, 2) void proj_gemm(const u16* __restrict__ Xt,
                                                    const u16* __restrict__ Wp,
                                                    const float* __restrict__ bb,
                                                    u16* __restrict__ outp){
  __shared__ __align__(16) char lds[32768];
  int t = threadIdx.x, w = t >> 6, l = t & 63, q = l & 15, g = l >> 4;
  int b = blockIdx.z;
  int n0 = blockIdx.x * 128, o0 = blockIdx.y * 128;
  int fs = ((q >> 1) & 3) << 4;
  int partg = ((l & 3) ^ ((l >> 3) & 3));
  f32x4 acc[4][4] = {};

  for (int it = 0; it < 4; ++it){
    __syncthreads();
#pragma unroll
    for (int j = 0; j < 8; ++j){
      int s = j*4 + w;
      int chunk = s >> 3;
      int off = (s & 7) * 1024;
      int row = (s & 7)*16 + (l >> 2);
      const char* gsrc;
      if (chunk < 2)
        gsrc = (const char*)(Wp + (size_t)(o0 + row)*Cc) + it*128 + chunk*64 + partg*16;
      else
        gsrc = (const char*)(Xt + ((size_t)b*Nc + n0 + row)*Cc) + it*128 + (chunk & 1)*64 + partg*16;
      load_lds16(gsrc, lds + chunk*8192 + off);
    }
    asm volatile("s_waitcnt vmcnt(0)" ::: "memory");
    __syncthreads();
#pragma unroll
    for (int kc = 0; kc < 2; ++kc){
      f16x8 fw[4], fx[4];
#pragma unroll
      for (int i = 0; i < 4; ++i){
        int wrow = (SW ? (w & 1) : (w >> 1))*64 + i*16 + q;
        int xrow = (SW ? (w >> 1) : (w & 1))*64 + i*16 + q;
        fw[i] = *(const f16x8*)(lds + kc*8192 + wrow*64 + ((g*16) ^ fs));
        fx[i] = *(const f16x8*)(lds + 16384 + kc*8192 + xrow*64 + ((g*16) ^ fs));
      }
#pragma unroll
      for (int i = 0; i < 4; ++i)
#pragma unroll
        for (int jj = 0; jj < 4; ++jj){
          if constexpr (!SW) acc[i][jj] = MFMA16(fw[i], fx[jj], acc[i][jj]);
          else               acc[i][jj] = MFMA16(fx[i], fw[jj], acc[i][jj]);
        }
    }
  }

  if constexpr (!SW) {
    f32x4 bias[4];
#pragma unroll
    for (int i = 0; i < 4; ++i) bias[i] = *(const f32x4*)(bb + o0 + (w>>1)*64 + i*16 + 4*g);
#pragma unroll
    for (int i = 0; i < 4; ++i)
#pragma unroll
      for (int jj = 0; jj < 4; ++jj){
        u16x4 pk;
#pragma unroll
        for (int r = 0; r < 4; ++r){
          float z = acc[i][jj][r] + bias[i][r];
          pk[r] = f2h(fmaxf(z, 0.f));
        }
        int o = o0 + (w>>1)*64 + i*16 + 4*g;
        int n = n0 + (w&1)*64 + jj*16 + q;
        int hh = o >> 8, d = o & 255;
        *(u16x4*)(outp + ((size_t)((b*Hc + hh)*Nc + n))*Dc + d) = pk;
      }
  } else {
    float biasv[4];
#pragma unroll
    for (int i = 0; i < 4; ++i) biasv[i] = bb[o0 + (w&1)*64 + i*16 + q];
#pragma unroll
    for (int i = 0; i < 4; ++i)
#pragma unroll
      for (int jj = 0; jj < 4; ++jj){
        u16x4 pk;
#pragma unroll
        for (int r = 0; r < 4; ++r){
          float z = acc[i][jj][r] + biasv[jj];
          pk[r] = f2h(fmaxf(z, 0.f));
        }
        int o = o0 + (w&1)*64 + jj*16 + q;
        int n = n0 + (w>>1)*64 + i*16 + 4*g;
        int hh = o >> 8, d = o & 255;
        *(u16x4*)(outp + ((size_t)((b*Hc + hh)*Dc + d))*Nc + n) = pk;
      }
  }
}

// ---------------- kernel 2: flash attention — wave-private softmax, LDS K+V ----------------
// 512 thr, 8 waves (wq 0..3 x wd 0..1), QBLK=128. Wave: 32 q, full m=64 (QK dup across wd),
// half d (acc 64 AGPR). Wave-local softmax + in-register P pack (R10-verified core).
// K dbuf [64m][512B] slot^5-bit (R8-verified clean); V dbuf [64r][512B], 4 d-rows/row,
// slot(d,m16) = (d&3)*8 + (m16 ^ ((d>>2)&7)) (roundtrip-verified). 1 barrier + 1 drain/iter.
// Register budget: qf 64 + pack/addr ~45 arch VGPR; s0/s1/acc in AGPR -> no spill.
__global__ __launch_bounds__(512, 1) void attn_kernel(const u16* __restrict__ Qp,
                                                      const u16* __restrict__ Kp,
                                                      const u16* __restrict__ Vp,
                                                      float* __restrict__ outp){
  __shared__ __align__(16) char lds[131072];   // K dbuf @0, V dbuf @65536
  const int t = threadIdx.x, w = t >> 6, l = t & 63, lq = l & 31, hi = l >> 5;
  const int wq = w & 3, wd = w >> 2;
  const int h = blockIdx.y, b = blockIdx.z;
  const int q0 = blockIdx.x * 128;
  size_t head = (size_t)(b*Hc + h) * Nc * Dc;
  const u16* Qh = Qp + head;
  const u16* Kh = Kp + head;
  const u16* Vh = Vp + head;

  // Q B-frags: lane(lq,hi) holds Q[q0+wq*32+lq][kc*16 + hi*8 + e]
  f16x8 qf[16];
  {
    const u16* qrow = Qh + (size_t)(q0 + wq*32 + lq) * Dc;
#pragma unroll
    for (int kc = 0; kc < 16; ++kc) qf[kc] = *(const f16x8*)(qrow + kc*16 + hi*8);
  }

  f32x16 acc[4] = {};                 // O[32q][d-half: dt 0..3, col d = wd*128+dt*32+lq]
  float m_run = -1e30f, l_run = 0.f;
  const int lsw = lq ^ ((lq >> 3) & 3);   // K read-side scramble

  // K staging: 8 waves x 4 insts x 2 rows(hi) = 64 rows; source chunk pre-scrambled
#define STAGE_K(m0_, buf_)                                                         \
  {                                                                                \
    char* Kd = lds + (buf_)*32768;                                                 \
    _Pragma("unroll")                                                              \
    for (int j = 0; j < 4; ++j){                                                   \
      int row = w*8 + j*2 + hi;                                                    \
      int r5 = row & 31;                                                           \
      int gs = (l & 31) ^ r5 ^ ((r5 >> 3) & 3);                                    \
      load_lds16(Kh + (size_t)((m0_) + row)*Dc + gs*8, Kd + w*4096 + j*1024);      \
    }                                                                              \
  }
  // V staging: 8 waves x 4 insts; unit u = w*4+j covers rows u*2+hi (64 rows of 512B).
  // LDS[r][slot s] = V^T[d = r*4 + (s>>3)][m16 = (s&7) ^ (r&7)]; lane writes slot l&31.
#define STAGE_V(m0_, buf_)                                                         \
  {                                                                                \
    char* Vd = lds + 65536 + (buf_)*32768;                                         \
    _Pragma("unroll")                                                              \
    for (int j = 0; j < 4; ++j){                                                   \
      int u = w*4 + j;                                                             \
      int r = u*2 + hi;                                                            \
      int d = r*4 + ((l >> 3) & 3);                                                \
      int m16 = (l & 7) ^ (r & 7);                                                 \
      load_lds16(Vh + (size_t)d*Nc + (m0_) + m16*8, Vd + u*1024);                  \
    }                                                                              \
  }

  STAGE_K(0, 0);
  STAGE_V(0, 0);
  asm volatile("s_waitcnt vmcnt(0)" ::: "memory");
  __syncthreads();

  for (int it = 0; it < 32; ++it){
    const int cur = it & 1;
    const int mn = ((it < 31) ? (it + 1) : 31) * 64;
    char* Kc = lds + cur*32768;
    char* Vc = lds + 65536 + cur*32768;

    // issue next tile's stage into the other buffer (drained at end of iter)
    STAGE_K(mn, cur ^ 1);
    STAGE_V(mn, cur ^ 1);

    // QK^T both strips: S^T[m 0..63][32 q]
    f32x16 s0 = {}, s1 = {};
    __builtin_amdgcn_s_setprio(1);
#pragma unroll
    for (int kc = 0; kc < 16; ++kc){
      int so = ((kc*2 + hi) ^ lsw) << 4;
      f16x8 kf0 = *(const f16x8*)(Kc + lq*512 + so);
      f16x8 kf1 = *(const f16x8*)(Kc + (32 + lq)*512 + so);
      s0 = MFMA32(kf0, qf[kc], s0);
      s1 = MFMA32(kf1, qf[kc], s1);
    }
    __builtin_amdgcn_s_setprio(0);

    // wave-local softmax (lane owns q-col lq, dup across hi)
    float tmax = s0[0];
#pragma unroll
    for (int r = 1; r < 16; ++r) tmax = fmaxf(tmax, s0[r]);
#pragma unroll
    for (int r = 0; r < 16; ++r) tmax = fmaxf(tmax, s1[r]);
    tmax = fmaxf(tmax, __shfl_xor(tmax, 32));

    float meff = m_run, scale = 1.f;
    if (!__all(tmax <= m_run + 8.f)){       // T13 defer-max
      meff = fmaxf(m_run, tmax);
      scale = __expf(m_run - meff);
      m_run = meff;
#pragma unroll
      for (int r = 0; r < 16; ++r){
        float scr = __shfl(scale, (r & 3) + 8*(r >> 2) + 4*hi);
#pragma unroll
        for (int dt = 0; dt < 4; ++dt) acc[dt][r] *= scr;
      }
    }

    float rsum = 0.f;
#pragma unroll
    for (int r = 0; r < 16; ++r){ s0[r] = __expf(s0[r] - meff); rsum += s0[r]; }
#pragma unroll
    for (int r = 0; r < 16; ++r){ s1[r] = __expf(s1[r] - meff); rsum += s1[r]; }
    rsum += __shfl_xor(rsum, 32);
    l_run = l_run * scale + rsum;

    // pack P in-register (verified): strip0 -> a0,a1 ; strip1 -> a2,a3
    f16x8 a0, a1, a2, a3;
    {
      int pk[8], sx[8];
#pragma unroll
      for (int j2 = 0; j2 < 8; ++j2)
        pk[j2] = __builtin_bit_cast(int, __builtin_amdgcn_cvt_pkrtz(s0[2*j2], s0[2*j2+1]));
#pragma unroll
      for (int j2 = 0; j2 < 8; ++j2) sx[j2] = __shfl_xor(pk[j2], 32);
      i32x4 c0, c1;
      c0[0] = hi ? sx[2] : pk[0];  c0[1] = hi ? sx[3] : pk[1];
      c0[2] = hi ? pk[2] : sx[0];  c0[3] = hi ? pk[3] : sx[1];
      c1[0] = hi ? sx[6] : pk[4];  c1[1] = hi ? sx[7] : pk[5];
      c1[2] = hi ? pk[6] : sx[4];  c1[3] = hi ? pk[7] : sx[5];
      a0 = __builtin_bit_cast(f16x8, c0);
      a1 = __builtin_bit_cast(f16x8, c1);
    }
    {
      int pk[8], sx[8];
#pragma unroll
      for (int j2 = 0; j2 < 8; ++j2)
        pk[j2] = __builtin_bit_cast(int, __builtin_amdgcn_cvt_pkrtz(s1[2*j2], s1[2*j2+1]));
#pragma unroll
      for (int j2 = 0; j2 < 8; ++j2) sx[j2] = __shfl_xor(pk[j2], 32);
      i32x4 c0, c1;
      c0[0] = hi ? sx[2] : pk[0];  c0[1] = hi ? sx[3] : pk[1];
      c0[2] = hi ? pk[2] : sx[0];  c0[3] = hi ? pk[3] : sx[1];
      c1[0] = hi ? sx[6] : pk[4];  c1[1] = hi ? sx[7] : pk[5];
      c1[2] = hi ? pk[6] : sx[4];  c1[3] = hi ? pk[7] : sx[5];
      a2 = __builtin_bit_cast(f16x8, c0);
      a3 = __builtin_bit_cast(f16x8, c1);
    }

    // PV: O[32q][d-half] += P · V ; V frags from LDS (conflict-free slot map)
    __builtin_amdgcn_s_setprio(1);
#pragma unroll
    for (int dt = 0; dt < 4; ++dt){
      int vrow = wd*32 + dt*8 + (lq >> 2);
#pragma unroll
      for (int ks = 0; ks < 4; ++ks){
        int slot = (lq & 3)*8 + ((ks*2 + hi) ^ (lq >> 2));
        f16x8 vf = *(const f16x8*)(Vc + vrow*512 + slot*16);
        f16x8 af = (ks == 0) ? a0 : (ks == 1) ? a1 : (ks == 2) ? a2 : a3;
        acc[dt] = MFMA32(af, vf, acc[dt]);
      }
    }
    __builtin_amdgcn_s_setprio(0);

    // drain next-tile stage; swap buffers
    asm volatile("s_waitcnt vmcnt(0)" ::: "memory");
    __syncthreads();
  }
#undef STAGE_K
#undef STAGE_V

  float inv_own = 1.f / l_run;
#pragma unroll
  for (int r = 0; r < 16; ++r){
    int crow = (r & 3) + 8*(r >> 2) + 4*hi;
    float invr = __shfl(inv_own, crow);
    size_t obase = head + (size_t)(q0 + wq*32 + crow)*Dc + wd*128 + lq;
#pragma unroll
    for (int dt = 0; dt < 4; ++dt)
      outp[obase + dt*32] = acc[dt][r] * invr;
  }
}

// ---------------- launch ----------------
extern "C" void kernel_launch(void* const* d_in, const int* in_sizes, int n_in,
                              void* d_out, int out_size, void* d_ws, size_t ws_size,
                              hipStream_t stream){
  const float* x     = (const float*)d_in[0];
  const float* y     = (const float*)d_in[1];
  const float* Wq    = (const float*)d_in[2];
  const float* bq    = (const float*)d_in[3];
  const float* gq    = (const float*)d_in[4];
  const float* betaq = (const float*)d_in[5];
  const float* Wk    = (const float*)d_in[6];
  const float* bk    = (const float*)d_in[7];
  const float* gk    = (const float*)d_in[8];
  const float* betak = (const float*)d_in[9];
  const float* Wv    = (const float*)d_in[10];
  const float* bv    = (const float*)d_in[11];
  const float* gv    = (const float*)d_in[12];
  const float* betav = (const float*)d_in[13];
  char* ws = (char*)d_ws;
  float* outp = (float*)d_out;

  u16* XT = (u16*)(ws + OFF_XT);
  u16* YT = (u16*)(ws + OFF_YT);
  u16* WQb = (u16*)(ws + OFF_WQ);
  u16* WKb = (u16*)(ws + OFF_WK);
  u16* WVb = (u16*)(ws + OFF_WV);
  float* BQ = (float*)(ws + OFF_BQ);
  float* BK = (float*)(ws + OFF_BK);
  float* BV = (float*)(ws + OFF_BV);
  u16* Qw = (u16*)(ws + OFF_Q);
  u16* Kw = (u16*)(ws + OFF_K);
  u16* Vw = (u16*)(ws + OFF_V);

  transpose_cast<<<dim3(Nc/64, Cc/64, Bc*2), 256, 0, stream>>>(x, y, XT, YT);
  prep_w<<<dim3(OCc*Cc/2048), 256, 0, stream>>>(Wq, bq, gq, betaq, WQb, BQ);
  prep_w<<<dim3(OCc*Cc/2048), 256, 0, stream>>>(Wk, bk, gk, betak, WKb, BK);
  prep_w<<<dim3(OCc*Cc/2048), 256, 0, stream>>>(Wv, bv, gv, betav, WVb, BV);

  dim3 pg(Nc/128, OCc/128, Bc);
  proj_gemm<0><<<pg, 256, 0, stream>>>(XT, WQb, BQ, Qw);
  proj_gemm<0><<<pg, 256, 0, stream>>>(YT, WKb, BK, Kw);
  proj_gemm<1><<<pg, 256, 0, stream>>>(YT, WVb, BV, Vw);

  attn_kernel<<<dim3(Nc/128, Hc, Bc), 512, 0, stream>>>(Qw, Kw, Vw, outp);
}